// Round 5
// baseline (1186.193 us; speedup 1.0000x reference)
//
#include <hip/hip_runtime.h>
#include <hip/hip_bf16.h>

#define N_NODES 50000
#define N_EDGES 500000
#define DIM_A 128
#define SCAN_B 49        // ceil(50000/1024)

typedef __attribute__((ext_vector_type(8))) short short8;
typedef __attribute__((ext_vector_type(8))) unsigned short ushort8;
typedef __attribute__((ext_vector_type(4))) float f32x4;
typedef unsigned short ushort;
typedef unsigned int uint;

__device__ __forceinline__ ushort f2bf(float x) {
    __hip_bfloat16 h = __float2bfloat16(x);
    return *reinterpret_cast<ushort*>(&h);
}
__device__ __forceinline__ float bf2f(ushort u) {
    union { float f; unsigned int i; } v; v.i = ((unsigned int)u) << 16; return v.f;
}
__device__ __forceinline__ float leaky(float x) {
    return x >= 0.f ? x : 0.1f * x;
}

// ---------------- weight conversion ----------------
__global__ __launch_bounds__(256) void convw_kernel(
    const float* __restrict__ Wy000, const float* __restrict__ Wy110,
    const float* __restrict__ Wy011, const float* __restrict__ Wy101,
    const float* __restrict__ Wy111,
    const float* __restrict__ Wm1, const float* __restrict__ Wm2,
    const float* __restrict__ Wm3,
    ushort* __restrict__ W0b, ushort* __restrict__ Wm1b,
    ushort* __restrict__ Wm2b, ushort* __restrict__ Wm3b,
    ushort* __restrict__ W011b, ushort* __restrict__ W101b,
    ushort* __restrict__ W111b)
{
    int g = blockIdx.x * 256 + threadIdx.x;
    if (g < 128 * 64) {           // W0b[o][c]: c<32 -> Wy000, else Wy110
        int o = g >> 6, c = g & 63;
        float v = (c < 32) ? Wy000[o * 32 + c] : Wy110[o * 32 + (c - 32)];
        W0b[g] = f2bf(v);
    }
    if (g < 128 * 128) {
        Wm1b[g] = f2bf(Wm1[g]);
        Wm2b[g] = f2bf(Wm2[g]);
        Wm3b[g] = f2bf(Wm3[g]);
    }
    if (g < 32 * 32) {
        W011b[g] = f2bf(Wy011[g]);
        W101b[g] = f2bf(Wy101[g]);
        W111b[g] = f2bf(Wy111[g]);
    }
}

// ---------------- node projection: LN[n][128] = [L0(32) | L1(96, c*3+i)] ----
__global__ __launch_bounds__(256) void node_proj_kernel(
    const float* __restrict__ x_a, const float* __restrict__ x_v,
    const float* __restrict__ W_L0, const float* __restrict__ W_L1,
    float* __restrict__ LN)
{
    int t = threadIdx.x;
    int n = blockIdx.x * 8 + (t >> 5);
    int c = t & 31;
    if (n >= N_NODES) return;

    const float4* xa = (const float4*)(x_a + (size_t)n * DIM_A);
    const float4* w0 = (const float4*)(W_L0 + c * DIM_A);
    float acc = 0.f;
#pragma unroll 8
    for (int k = 0; k < DIM_A / 4; ++k) {
        float4 x = xa[k]; float4 w = w0[k];
        acc += x.x * w.x + x.y * w.y + x.z * w.z + x.w * w.w;
    }
    LN[(size_t)n * 128 + c] = acc;

    const float* xv = x_v + (size_t)n * 32 * 3;
    const float* w1 = W_L1 + c * 32;
    float a0 = 0.f, a1 = 0.f, a2 = 0.f;
#pragma unroll 8
    for (int d = 0; d < 32; ++d) {
        float w = w1[d];
        a0 += xv[d * 3 + 0] * w;
        a1 += xv[d * 3 + 1] * w;
        a2 += xv[d * 3 + 2] * w;
    }
    float* o = LN + (size_t)n * 128 + 32 + c * 3;
    o[0] = a0; o[1] = a1; o[2] = a2;
}

// ---------------- dual histogram ----------------
__global__ __launch_bounds__(256) void hist2_kernel(
    const int* __restrict__ src, const int* __restrict__ dst,
    int* __restrict__ degS, int* __restrict__ degD)
{
    int i = blockIdx.x * 256 + threadIdx.x;
    if (i < N_EDGES) {
        atomicAdd(&degS[src[i]], 1);
        atomicAdd(&degD[dst[i]], 1);
    }
}

// ---------------- 3-phase multi-block exclusive scan ----------------
__global__ __launch_bounds__(1024) void scan1_kernel(const int* __restrict__ deg,
                                                     int* __restrict__ excl,
                                                     int* __restrict__ bsum)
{
    __shared__ int buf[1024];
    int t = threadIdx.x;
    int i = blockIdx.x * 1024 + t;
    int v = (i < N_NODES) ? deg[i] : 0;
    buf[t] = v;
    __syncthreads();
    for (int off = 1; off < 1024; off <<= 1) {
        int x = (t >= off) ? buf[t - off] : 0;
        __syncthreads();
        buf[t] += x;
        __syncthreads();
    }
    if (i < N_NODES) excl[i] = buf[t] - v;
    if (t == 1023) bsum[blockIdx.x] = buf[1023];
}

__global__ void scan2_kernel(int* __restrict__ bsum)
{
    if (threadIdx.x == 0) {
        int s = 0;
        for (int k = 0; k < SCAN_B; ++k) { int x = bsum[k]; bsum[k] = s; s += x; }
    }
}

__global__ __launch_bounds__(1024) void scan3_kernel(const int* __restrict__ excl,
                                                     const int* __restrict__ bsum,
                                                     int* __restrict__ offs,
                                                     int* __restrict__ cursor)
{
    int t = threadIdx.x;
    int i = blockIdx.x * 1024 + t;
    if (i < N_NODES) {
        int o = excl[i] + bsum[blockIdx.x];
        offs[i] = o;
        cursor[i] = o;
    }
    if (i == 0) offs[N_NODES] = N_EDGES;
}

// ---------------- scatters ----------------
__global__ __launch_bounds__(256) void scatterS_kernel(const int* __restrict__ src,
                                                       int* __restrict__ curS,
                                                       int* __restrict__ srcPos,
                                                       int* __restrict__ rowNode)
{
    int i = blockIdx.x * 256 + threadIdx.x;
    if (i < N_EDGES) {
        int s = src[i];
        int p = atomicAdd(&curS[s], 1);
        srcPos[i] = p;
        rowNode[p] = s;
    }
}

__global__ __launch_bounds__(256) void scatterD_kernel(
    const int* __restrict__ dst, const float* __restrict__ r_ij,
    const int* __restrict__ srcPos, int* __restrict__ curD,
    float4* __restrict__ edgeD, int* __restrict__ e2d)
{
    int i = blockIdx.x * 256 + threadIdx.x;
    if (i < N_EDGES) {
        int d = dst[i];
        int p = atomicAdd(&curD[d], 1);
        edgeD[p] = make_float4(r_ij[i * 3 + 0], r_ij[i * 3 + 1], r_ij[i * 3 + 2],
                               __int_as_float(d));
        e2d[srcPos[i]] = p;   // src-slot -> storage row (dst order)
    }
}

// ---------------- kernel A: features + psi_v + psi0 (weights in LDS) --------
// LDS 48640 B, 3 blocks/CU. 64 edges/block, 4 waves, wave owns rows [16w,16w+16).
__global__ __launch_bounds__(256, 3) void edge_feat_kernel(
    const float4* __restrict__ edgeD, const float* __restrict__ LN,
    const float* __restrict__ W_enc, const float* __restrict__ b_enc,
    const ushort* __restrict__ W0b, const ushort* __restrict__ W011b,
    const ushort* __restrict__ W101b, const ushort* __restrict__ W111b,
    ushort* __restrict__ psi0, ushort* __restrict__ psiV)
{
    __shared__ __align__(16) ushort sm[24320];
    // sY0   : us [0, 4608)        64 x 72
    // sRS   : us [4608, 5120)     64 x 4 floats (256 f)
    // R     : us [5120, 15104)    sRELV 64x104 (6656) + sWv 32x104 (3328)
    //         later overlaid by sACT 64x136 (8704) for psi0
    // sW0   : us [15104, 24320)   128 x 72
    ushort* sY0   = sm;
    float*  sRS   = (float*)(sm + 4608);
    ushort* sRELV = sm + 5120;
    ushort* sWv   = sm + 5120 + 6656;
    ushort* sACT  = sm + 5120;
    ushort* sW0   = sm + 15104;

    const int t = threadIdx.x;
    const int e0 = blockIdx.x * 64;

    // stage W0 (128 x 64 -> stride 72): 1024 chunks of 8 us, 4/thread
#pragma unroll
    for (int k = 0; k < 4; ++k) {
        int ch = t + k * 256;
        int row = ch >> 3, c8 = ch & 7;
        *(ushort8*)&sW0[row * 72 + c8 * 8] = *(const ushort8*)&W0b[row * 64 + c8 * 8];
    }
    // stage Wv (3 mats 32x32 -> [d][m*32+c], stride 104): 3072 scalars, 12/thread
#pragma unroll
    for (int k = 0; k < 12; ++k) {
        int idx = t + k * 256;
        int m = idx >> 10, rem = idx & 1023;
        int d = rem >> 5, c = rem & 31;
        const ushort* srcw = (m == 0) ? W011b : (m == 1) ? W101b : W111b;
        sWv[d * 104 + m * 32 + c] = srcw[d * 32 + c];
    }

    // ---- phase 1: per-edge features -> LDS (own-wave rows) ----
    {
        const int e = t >> 2;          // wave w owns e in [16w,16w+16)
        const int p = t & 3;           // 8 channels each
        const int qe = min(e0 + e, N_EDGES - 1);
        float4 ed = edgeD[qe];
        float rx = ed.x, ry = ed.y, rz = ed.z;
        int dn = __float_as_int(ed.w);
        float r = sqrtf(rx * rx + ry * ry + rz * rz);

        float rad[8];
#pragma unroll
        for (int k = 0; k < 8; ++k) {
            float d = (r - (5.0f / 7.0f) * (float)k) * 1.6f;
            rad[k] = __expf(-d * d);
        }
        float n14 = 1.4f * r;
        float ee = __expf(2.f * n14);
        float tt = (ee - 1.f) / ((ee + 1.f) * fmaxf(n14, 1e-6f));
        float rsx = 1.4f * rx * tt, rsy = 1.4f * ry * tt, rsz = 1.4f * rz * tt;
        if (p == 0) {
            sRS[e * 4 + 0] = rsx;
            sRS[e * 4 + 1] = rsy;
            sRS[e * 4 + 2] = rsz;
        }

        float la[8];
        {
            const float4* lap = (const float4*)(LN + (size_t)dn * 128 + p * 8);
            float4 A = lap[0], B = lap[1];
            la[0] = A.x; la[1] = A.y; la[2] = A.z; la[3] = A.w;
            la[4] = B.x; la[5] = B.y; la[6] = B.z; la[7] = B.w;
        }
        float lv[24];
        {
            const float4* lvp = (const float4*)(LN + (size_t)dn * 128 + 32 + p * 24);
#pragma unroll
            for (int q = 0; q < 6; ++q) {
                float4 v = lvp[q];
                lv[q * 4 + 0] = v.x; lv[q * 4 + 1] = v.y;
                lv[q * 4 + 2] = v.z; lv[q * 4 + 3] = v.w;
            }
        }

        ushort8 u000, u110, url[3];
#pragma unroll
        for (int j = 0; j < 8; ++j) {
            int c = p * 8 + j;
            float re = b_enc[c];
#pragma unroll
            for (int k = 0; k < 8; ++k) re += rad[k] * W_enc[c * 8 + k];
            float lvx = lv[j * 3 + 0], lvy = lv[j * 3 + 1], lvz = lv[j * 3 + 2];
            float dotv = lvx * rsx + lvy * rsy + lvz * rsz;
            u000[j] = f2bf(la[j] * re);
            u110[j] = f2bf(re * dotv);
            url[0][j] = f2bf(re * lvx);
            url[1][j] = f2bf(re * lvy);
            url[2][j] = f2bf(re * lvz);
        }
        *(ushort8*)&sY0[e * 72 + p * 8]      = u000;
        *(ushort8*)&sY0[e * 72 + 32 + p * 8] = u110;
#pragma unroll
        for (int i = 0; i < 3; ++i)
            *(ushort8*)&sRELV[e * 104 + i * 32 + p * 8] = url[i];
    }
    __syncthreads();   // staged weights + features visible

    const int lane = t & 63;
    const int w = t >> 6;
    const int r0 = lane & 15;
    const int quad = lane >> 4;
    const int arow = w * 16 + r0;

    // ---- psi_v: psiV[d] = s[d]*rs + T[d] + U[d] x rs ----
    {
        short8 aY0 = *(const short8*)&sY0[arow * 72 + quad * 8];
        short8 aRL[3];
#pragma unroll
        for (int i = 0; i < 3; ++i)
            aRL[i] = *(const short8*)&sRELV[arow * 104 + i * 32 + quad * 8];

#pragma unroll
        for (int nt = 0; nt < 2; ++nt) {
            const int d = nt * 16 + r0;
            short8 b011 = *(const short8*)&sWv[d * 104 + 0  + quad * 8];
            short8 b101 = *(const short8*)&sWv[d * 104 + 32 + quad * 8];
            short8 b111 = *(const short8*)&sWv[d * 104 + 64 + quad * 8];
            f32x4 sA = __builtin_amdgcn_mfma_f32_16x16x32_bf16(
                aY0, b011, (f32x4){0.f, 0.f, 0.f, 0.f}, 0, 0, 0);
            f32x4 T[3], U[3];
#pragma unroll
            for (int i = 0; i < 3; ++i) {
                T[i] = __builtin_amdgcn_mfma_f32_16x16x32_bf16(
                    aRL[i], b101, (f32x4){0.f, 0.f, 0.f, 0.f}, 0, 0, 0);
                U[i] = __builtin_amdgcn_mfma_f32_16x16x32_bf16(
                    aRL[i], b111, (f32x4){0.f, 0.f, 0.f, 0.f}, 0, 0, 0);
            }
#pragma unroll
            for (int rr = 0; rr < 4; ++rr) {
                int el = w * 16 + quad * 4 + rr;
                float rsx = sRS[el * 4 + 0];
                float rsy = sRS[el * 4 + 1];
                float rsz = sRS[el * 4 + 2];
                float s = sA[rr];
                float ux = U[0][rr], uy = U[1][rr], uz = U[2][rr];
                float ox = s * rsx + T[0][rr] + uy * rsz - uz * rsy;
                float oy = s * rsy + T[1][rr] + uz * rsx - ux * rsz;
                float oz = s * rsz + T[2][rr] + ux * rsy - uy * rsx;
                // pack into own-wave region of sRELV: [w*1664, w*1664+1536)
                int pb = w * 1664 + (quad * 4 + rr) * 96;
                sRELV[pb + 0 * 32 + d] = f2bf(ox);
                sRELV[pb + 1 * 32 + d] = f2bf(oy);
                sRELV[pb + 2 * 32 + d] = f2bf(oz);
            }
        }
        // flat coalesced copy of wave's 16 psiV rows (3072 B)
#pragma unroll
        for (int i = 0; i < 3; ++i) {
            int c = lane + 64 * i;    // chunk of 8 us
            ushort8 v = *(const ushort8*)&sRELV[w * 1664 + c * 8];
            *(ushort8*)&psiV[(size_t)(e0 + w * 16) * 96 + c * 8] = v;
        }
    }
    __syncthreads();   // all psiV reads/copies done before sACT overlay

    // ---- psi0 = Y0 @ W0cat^T (K=64) -> sACT -> coalesced store ----
    {
        short8 aY[2];
        aY[0] = *(const short8*)&sY0[arow * 72 + quad * 8];
        aY[1] = *(const short8*)&sY0[arow * 72 + 32 + quad * 8];
#pragma unroll
        for (int nt = 0; nt < 8; ++nt) {
            f32x4 acc = {0.f, 0.f, 0.f, 0.f};
#pragma unroll
            for (int kb = 0; kb < 2; ++kb) {
                short8 b = *(const short8*)&sW0[(nt * 16 + r0) * 72 + kb * 32 + quad * 8];
                acc = __builtin_amdgcn_mfma_f32_16x16x32_bf16(aY[kb], b, acc, 0, 0, 0);
            }
#pragma unroll
            for (int rr = 0; rr < 4; ++rr)
                sACT[(w * 16 + quad * 4 + rr) * 136 + nt * 16 + r0] = f2bf(acc[rr]);
        }
        // flat coalesced copy of wave's 16 psi0 rows (4096 B)
#pragma unroll
        for (int i = 0; i < 4; ++i) {
            int c = lane + 64 * i;    // chunk of 8 us; row = c/16
            int row = c >> 4, c8 = c & 15;
            ushort8 v = *(const ushort8*)&sACT[(w * 16 + row) * 136 + c8 * 8];
            *(ushort8*)&psi0[(size_t)(e0 + w * 16 + row) * 128 + c8 * 8] = v;
        }
    }
}

// ---------------- kernel B: 3-layer MLP + residual, in-place on psi0 --------
// LDS 52224 B (sACT 64x136 + sW 128x136), 3 blocks/CU.
__device__ __forceinline__ void stage_w(ushort* sW, const ushort* W, int t) {
#pragma unroll
    for (int k = 0; k < 8; ++k) {
        int ch = t + k * 256;
        int row = ch >> 4, c8 = ch & 15;
        *(ushort8*)&sW[row * 136 + c8 * 8] = *(const ushort8*)&W[row * 128 + c8 * 8];
    }
}

__global__ __launch_bounds__(256, 3) void mlp_kernel(
    const ushort* __restrict__ Wm1b, const ushort* __restrict__ Wm2b,
    const ushort* __restrict__ Wm3b,
    const float* __restrict__ bm1, const float* __restrict__ bm2,
    ushort* __restrict__ psi0)
{
    __shared__ __align__(16) ushort sm[26112];
    ushort* sACT = sm;          // 64 x 136
    ushort* sW   = sm + 8704;   // 128 x 136

    const int t = threadIdx.x;
    const int e0 = blockIdx.x * 64;
    const int lane = t & 63, w = t >> 6;
    const int r0 = lane & 15, quad = lane >> 4;
    const int arow = w * 16 + r0;

    // A-frags of psi0 from global (coalesced-ish row gathers, L2-resident rows)
    short8 af[4];
#pragma unroll
    for (int kb = 0; kb < 4; ++kb)
        af[kb] = *(const short8*)&psi0[(size_t)(e0 + arow) * 128 + kb * 32 + quad * 8];

    stage_w(sW, Wm1b, t);
    __syncthreads();

    // h1
    {
        f32x4 hv[8];
#pragma unroll
        for (int nt = 0; nt < 8; ++nt) {
            float bv = bm1[nt * 16 + r0];
            f32x4 acc = {bv, bv, bv, bv};
#pragma unroll
            for (int kb = 0; kb < 4; ++kb) {
                short8 b = *(const short8*)&sW[(nt * 16 + r0) * 136 + kb * 32 + quad * 8];
                acc = __builtin_amdgcn_mfma_f32_16x16x32_bf16(af[kb], b, acc, 0, 0, 0);
            }
#pragma unroll
            for (int rr = 0; rr < 4; ++rr) acc[rr] = leaky(acc[rr]);
            hv[nt] = acc;
        }
#pragma unroll
        for (int nt = 0; nt < 8; ++nt)
#pragma unroll
            for (int rr = 0; rr < 4; ++rr)
                sACT[(w * 16 + quad * 4 + rr) * 136 + nt * 16 + r0] = f2bf(hv[nt][rr]);
    }
    __syncthreads();
    stage_w(sW, Wm2b, t);
    __syncthreads();

    // h2
    {
        short8 a2[4];
#pragma unroll
        for (int kb = 0; kb < 4; ++kb)
            a2[kb] = *(const short8*)&sACT[arow * 136 + kb * 32 + quad * 8];
        f32x4 hv[8];
#pragma unroll
        for (int nt = 0; nt < 8; ++nt) {
            float bv = bm2[nt * 16 + r0];
            f32x4 acc = {bv, bv, bv, bv};
#pragma unroll
            for (int kb = 0; kb < 4; ++kb) {
                short8 b = *(const short8*)&sW[(nt * 16 + r0) * 136 + kb * 32 + quad * 8];
                acc = __builtin_amdgcn_mfma_f32_16x16x32_bf16(a2[kb], b, acc, 0, 0, 0);
            }
#pragma unroll
            for (int rr = 0; rr < 4; ++rr) acc[rr] = leaky(acc[rr]);
            hv[nt] = acc;
        }
#pragma unroll
        for (int nt = 0; nt < 8; ++nt)
#pragma unroll
            for (int rr = 0; rr < 4; ++rr)
                sACT[(w * 16 + quad * 4 + rr) * 136 + nt * 16 + r0] = f2bf(hv[nt][rr]);
    }
    __syncthreads();
    stage_w(sW, Wm3b, t);
    __syncthreads();

    // h3 (no bias/act) -> sACT, then flat add-residual-store (in place)
    {
        short8 a3[4];
#pragma unroll
        for (int kb = 0; kb < 4; ++kb)
            a3[kb] = *(const short8*)&sACT[arow * 136 + kb * 32 + quad * 8];
        f32x4 hv[8];
#pragma unroll
        for (int nt = 0; nt < 8; ++nt) {
            f32x4 acc = {0.f, 0.f, 0.f, 0.f};
#pragma unroll
            for (int kb = 0; kb < 4; ++kb) {
                short8 b = *(const short8*)&sW[(nt * 16 + r0) * 136 + kb * 32 + quad * 8];
                acc = __builtin_amdgcn_mfma_f32_16x16x32_bf16(a3[kb], b, acc, 0, 0, 0);
            }
            hv[nt] = acc;
        }
#pragma unroll
        for (int nt = 0; nt < 8; ++nt)
#pragma unroll
            for (int rr = 0; rr < 4; ++rr)
                sACT[(w * 16 + quad * 4 + rr) * 136 + nt * 16 + r0] = f2bf(hv[nt][rr]);

#pragma unroll
        for (int i = 0; i < 4; ++i) {
            int c = lane + 64 * i;
            int row = c >> 4, c8 = c & 15;
            ushort8 h8 = *(const ushort8*)&sACT[(w * 16 + row) * 136 + c8 * 8];
            size_t g = (size_t)(e0 + w * 16 + row) * 128 + c8 * 8;
            ushort8 p8 = *(const ushort8*)&psi0[g];
            ushort8 o;
#pragma unroll
            for (int j = 0; j < 8; ++j) o[j] = f2bf(bf2f(h8[j]) + bf2f(p8[j]));
            *(ushort8*)&psi0[g] = o;
        }
    }
}

// ---------------- reduce v2: 16 nodes/block, row-parallel, LDS atomics ------
__global__ __launch_bounds__(256) void reduce2_kernel(
    const int* __restrict__ offsS, const int* __restrict__ e2d,
    const int* __restrict__ rowNode,
    const ushort* __restrict__ psiA, const ushort* __restrict__ psiV,
    float* __restrict__ B_a, float* __restrict__ B_v)
{
    __shared__ float accA[16 * 132];
    __shared__ float accV[16 * 100];
    const int t = threadIdx.x;
    const int n0 = blockIdx.x * 16;
    for (int i = t; i < 16 * 132; i += 256) accA[i] = 0.f;
    for (int i = t; i < 16 * 100; i += 256) accV[i] = 0.f;
    const int rs = offsS[n0], re = offsS[n0 + 16];
    __syncthreads();

    const int lane = t & 63, w = t >> 6;
    const uint* pA = (const uint*)psiA;
    const uint* pV = (const uint*)psiV;

    for (int idx = rs + w; idx < re; idx += 4) {
        int node = rowNode[idx] - n0;
        int row  = e2d[idx];
        uint ua = pA[(size_t)row * 64 + lane];
        atomicAdd(&accA[node * 132 + lane * 2 + 0], bf2f((ushort)(ua & 0xffff)));
        atomicAdd(&accA[node * 132 + lane * 2 + 1], bf2f((ushort)(ua >> 16)));
        if (lane < 48) {
            uint uv = pV[(size_t)row * 48 + lane];
            atomicAdd(&accV[node * 100 + lane * 2 + 0], bf2f((ushort)(uv & 0xffff)));
            atomicAdd(&accV[node * 100 + lane * 2 + 1], bf2f((ushort)(uv >> 16)));
        }
    }
    __syncthreads();

    for (int i = t; i < 16 * 128; i += 256) {
        int node = i >> 7, col = i & 127;
        B_a[(size_t)(n0 + node) * 128 + col] = 0.1f * accA[node * 132 + col];
    }
    for (int i = t; i < 16 * 96; i += 256) {
        int node = i / 96, j = i % 96;   // stored col j = dir*32 + chan
        B_v[(size_t)(n0 + node) * 96 + (j & 31) * 3 + (j >> 5)] = 0.1f * accV[node * 100 + j];
    }
}

extern "C" void kernel_launch(void* const* d_in, const int* in_sizes, int n_in,
                              void* d_out, int out_size, void* d_ws, size_t ws_size,
                              hipStream_t stream) {
    const float* x_a   = (const float*)d_in[0];
    const float* x_v   = (const float*)d_in[1];
    const float* r_ij  = (const float*)d_in[2];
    const int*   src   = (const int*)d_in[3];
    const int*   dst   = (const int*)d_in[4];
    const float* W_L0  = (const float*)d_in[5];
    const float* W_L1  = (const float*)d_in[6];
    const float* W_enc = (const float*)d_in[7];
    const float* b_enc = (const float*)d_in[8];
    const float* Wy000 = (const float*)d_in[9];
    const float* Wy110 = (const float*)d_in[10];
    const float* Wy011 = (const float*)d_in[11];
    const float* Wy101 = (const float*)d_in[12];
    const float* Wy111 = (const float*)d_in[13];
    const float* Wm1   = (const float*)d_in[14];
    const float* bm1   = (const float*)d_in[15];
    const float* Wm2   = (const float*)d_in[16];
    const float* bm2   = (const float*)d_in[17];
    const float* Wm3   = (const float*)d_in[18];

    float* out = (float*)d_out;
    float* B_a = out;
    float* B_v = out + (size_t)N_NODES * DIM_A;

    char* wp = (char*)d_ws;
    float* LN     = (float*)wp;  wp += (size_t)N_NODES * 128 * 4;   // 25.6 MB
    int*   degS   = (int*)wp;    wp += (size_t)N_NODES * 4;
    int*   degD   = (int*)wp;    wp += (size_t)N_NODES * 4;
    int*   offsS  = (int*)wp;    wp += (size_t)(N_NODES + 16) * 4;
    int*   curS   = (int*)wp;    wp += (size_t)N_NODES * 4;
    int*   offsD  = (int*)wp;    wp += (size_t)(N_NODES + 16) * 4;
    int*   curD   = (int*)wp;    wp += (size_t)N_NODES * 4;
    int*   excl   = (int*)wp;    wp += (size_t)N_NODES * 4;
    int*   bsum   = (int*)wp;    wp += 64 * 4;
    int*   e2d    = (int*)wp;    wp += (size_t)N_EDGES * 4;
    int*   rowNode= (int*)wp;    wp += (size_t)N_EDGES * 4;
    float4* edgeD = (float4*)wp; wp += (size_t)N_EDGES * 16;
    ushort* W0b   = (ushort*)wp; wp += 128 * 64 * 2;
    ushort* Wm1b  = (ushort*)wp; wp += 128 * 128 * 2;
    ushort* Wm2b  = (ushort*)wp; wp += 128 * 128 * 2;
    ushort* Wm3b  = (ushort*)wp; wp += 128 * 128 * 2;
    ushort* W011b = (ushort*)wp; wp += 32 * 32 * 2;
    ushort* W101b = (ushort*)wp; wp += 32 * 32 * 2;
    ushort* W111b = (ushort*)wp; wp += 32 * 32 * 2;
    ushort* psi0  = (ushort*)wp; wp += (size_t)(N_EDGES + 96) * 128 * 2; // 128 MB, in-place psiA
    ushort* psiV  = (ushort*)wp; wp += (size_t)(N_EDGES + 96) * 96 * 2;  // 96 MB
    int*   srcPos = (int*)psi0;  // alias: consumed (scatterD) before kernel A writes psi0

    hipMemsetAsync(degS, 0, 2 * N_NODES * sizeof(int), stream);  // degS+degD adjacent

    convw_kernel<<<64, 256, 0, stream>>>(Wy000, Wy110, Wy011, Wy101, Wy111,
                                         Wm1, Wm2, Wm3,
                                         W0b, Wm1b, Wm2b, Wm3b, W011b, W101b, W111b);
    node_proj_kernel<<<(N_NODES + 7) / 8, 256, 0, stream>>>(x_a, x_v, W_L0, W_L1, LN);

    hist2_kernel<<<(N_EDGES + 255) / 256, 256, 0, stream>>>(src, dst, degS, degD);

    scan1_kernel<<<SCAN_B, 1024, 0, stream>>>(degS, excl, bsum);
    scan2_kernel<<<1, 64, 0, stream>>>(bsum);
    scan3_kernel<<<SCAN_B, 1024, 0, stream>>>(excl, bsum, offsS, curS);

    scan1_kernel<<<SCAN_B, 1024, 0, stream>>>(degD, excl, bsum);
    scan2_kernel<<<1, 64, 0, stream>>>(bsum);
    scan3_kernel<<<SCAN_B, 1024, 0, stream>>>(excl, bsum, offsD, curD);

    scatterS_kernel<<<(N_EDGES + 255) / 256, 256, 0, stream>>>(src, curS, srcPos, rowNode);
    scatterD_kernel<<<(N_EDGES + 255) / 256, 256, 0, stream>>>(dst, r_ij, srcPos, curD,
                                                               edgeD, e2d);

    const int nblk = (N_EDGES + 63) / 64;   // 7813
    edge_feat_kernel<<<nblk, 256, 0, stream>>>(edgeD, LN, W_enc, b_enc,
                                               W0b, W011b, W101b, W111b, psi0, psiV);
    mlp_kernel<<<nblk, 256, 0, stream>>>(Wm1b, Wm2b, Wm3b, bm1, bm2, psi0);

    reduce2_kernel<<<N_NODES / 16, 256, 0, stream>>>(offsS, e2d, rowNode,
                                                     psi0, psiV, B_a, B_v);
}